// Round 19
// baseline (648.110 us; speedup 1.0000x reference)
//
#include <hip/hip_runtime.h>
#include <hip/hip_bf16.h>
#include <hip/hip_cooperative_groups.h>
#include <cstdio>

namespace cg = cooperative_groups;

typedef __hip_bfloat16 bf16;
typedef __attribute__((ext_vector_type(8))) short v8s;
typedef __attribute__((ext_vector_type(4))) short v4s;
typedef __attribute__((ext_vector_type(4))) float v4f;
typedef __attribute__((ext_vector_type(4))) double v4d;

#define MFMA16(a, b, c) __builtin_amdgcn_mfma_f32_16x16x32_bf16((a), (b), (c), 0, 0, 0)

#define NN 8192
#define DIN 128
#define DH 64
#define DOUT 32
#define KKEEP 4096
#define SPLITS 16  // k2 kv-splits
#define SPATT 16   // k4 kv-splits (matched to SPLITS for uniform fused blocks)
#define RS2 0.70710678118654752440

__device__ __forceinline__ float bf2f(bf16 v) { return __bfloat162float(v); }
__device__ __forceinline__ short f2bfs(float f) {
  __hip_bfloat16 h = __float2bfloat16(f);
  return *reinterpret_cast<short*>(&h);
}
__device__ __forceinline__ bf16 f2bf(float v) { return __float2bfloat16(v); }

// f64 exp, rel err ~7e-12 over |s|<=25
__device__ __forceinline__ double exp_d(double s) {
  const double L2E    = 1.4426950408889634074;
  const double LN2_HI = 6.93147180369123816490e-01;
  const double LN2_LO = 1.90821492927058770002e-10;
  double t  = s * L2E;
  double kf = rint(t);
  double r  = fma(-kf, LN2_HI, s);
  r = fma(-kf, LN2_LO, r);
  double p = 1.0 / 362880.0;
  p = fma(p, r, 1.0 / 40320.0);
  p = fma(p, r, 1.0 / 5040.0);
  p = fma(p, r, 1.0 / 720.0);
  p = fma(p, r, 1.0 / 120.0);
  p = fma(p, r, 1.0 / 24.0);
  p = fma(p, r, 1.0 / 6.0);
  p = fma(p, r, 0.5);
  p = fma(p, r, 1.0);
  p = fma(p, r, 1.0);
  int k = (int)kf;
  long long bits = ((long long)(1023 + k)) << 52;
  double sc = __longlong_as_double(bits);
  return p * sc;
}

// ---------------- K1: u inline; Q(pre-scaled),K f64; Qb,Kb,V^T bf16; w = V.u ----------------
__global__ __launch_bounds__(256) void k1_prep(
    const float* __restrict__ x, const float* __restrict__ Wq, const float* __restrict__ bq,
    const float* __restrict__ Wk, const float* __restrict__ bk, const float* __restrict__ Wv,
    const float* __restrict__ bv, const float* __restrict__ gW, const float* __restrict__ sW,
    double* __restrict__ Qd, double* __restrict__ Kd, double* __restrict__ w,
    bf16* __restrict__ Qb, bf16* __restrict__ Kb, bf16* __restrict__ Vt) {
  __shared__ double xs[16][DIN];
  int t = threadIdx.x;
  int nb = blockIdx.x * 16;
  for (int idx = t; idx < 16 * DIN; idx += 256)
    xs[idx >> 7][idx & 127] = (double)x[(size_t)nb * DIN + idx];
  __syncthreads();
  int d = t & 63;
  int sub = t >> 6;
  double ud = 0.0;
  for (int dd = 0; dd < DH; ++dd) ud = fma((double)gW[d * DH + dd], (double)sW[dd], ud);
  double bqd = (double)bq[d];
  double bkd = (double)bk[d];
  double bvd = (double)bv[d];
  for (int pass = 0; pass < 4; ++pass) {
    int n = pass * 4 + sub;
    double aq = bqd, ak = bkd, av = bvd;
#pragma unroll 8
    for (int c = 0; c < DIN; ++c) {
      double xv = xs[n][c];
      aq = fma(xv, (double)Wq[c * DH + d], aq);
      ak = fma(xv, (double)Wk[c * DH + d], ak);
      av = fma(xv, (double)Wv[c * DH + d], av);
    }
    aq *= 0.125;  // fold 1/sqrt(64), exact
    int node = nb + n;
    Qd[(size_t)node * DH + d] = aq;
    Kd[(size_t)node * DH + d] = ak;
    Qb[(size_t)node * DH + d] = f2bf((float)aq);
    Kb[(size_t)node * DH + d] = f2bf((float)ak);
    Vt[(size_t)d * NN + node] = f2bf((float)av);
    double pw = av * ud;
#pragma unroll
    for (int off = 32; off; off >>= 1) pw += __shfl_xor(pw, off);
    if (d == 0) w[node] = pw;
  }
}

// ---------------- K24: uniform sequential fusion — phase A = k2 chunk, phase B = k4 chunk --
__global__ __launch_bounds__(256) void k24_seq(
    const double* __restrict__ Qd, const double* __restrict__ Kd, const double* __restrict__ w,
    double* __restrict__ Zp, double* __restrict__ Wp, double* __restrict__ Ep, int* __restrict__ Jp,
    const bf16* __restrict__ Qb, const bf16* __restrict__ Kb, const bf16* __restrict__ Vt,
    float* __restrict__ hp, float* __restrict__ zp) {
  __shared__ __align__(16) char smem[16896];  // union: Kbuf[2][16][66] f64 | P[4][640] short
  const int t = threadIdx.x;
  const int wv = t >> 6;
  const int l = t & 63;

  // =================== phase A: k2 (r15 proven body) ===================
  {
    double (*Kbuf)[16][66] = (double (*)[16][66])smem;
    const int li = l & 15, lg = l >> 4;
    const int rb = (blockIdx.x & 127) * 64;
    const int sp = blockIdx.x >> 7;  // 0..SPLITS-1
    const int cbeg = sp * (NN / SPLITS);

    double qreg[16];
    const double* qrow = Qd + (size_t)(rb + 16 * wv + li) * DH + lg;
#pragma unroll
    for (int tt = 0; tt < 16; ++tt) qreg[tt] = qrow[4 * tt];

    {
      const double* src = Kd + (size_t)cbeg * DH;
      int r = t >> 4, c = (t & 15) * 4;
      *(double2*)&Kbuf[0][r][c]     = *(const double2*)&src[r * DH + c];
      *(double2*)&Kbuf[0][r][c + 2] = *(const double2*)&src[r * DH + c + 2];
    }
    __syncthreads();

    double Zt[4] = {0, 0, 0, 0}, Wt[4] = {0, 0, 0, 0}, Et[4] = {-1, -1, -1, -1};
    int Jt[4] = {0, 0, 0, 0};

    const int NT = (NN / SPLITS) / 16;  // 32 tiles
    for (int kt = 0; kt < NT; ++kt) {
      const int buf = kt & 1;
      if (kt + 1 < NT) {
        const double* src = Kd + (size_t)(cbeg + (kt + 1) * 16) * DH;
        int r = t >> 4, c = (t & 15) * 4;
        *(double2*)&Kbuf[buf ^ 1][r][c]     = *(const double2*)&src[r * DH + c];
        *(double2*)&Kbuf[buf ^ 1][r][c + 2] = *(const double2*)&src[r * DH + c + 2];
      }
      v4d acc = (v4d){0.0, 0.0, 0.0, 0.0};
      __builtin_amdgcn_s_setprio(1);
#pragma unroll
      for (int tt = 0; tt < 16; ++tt) {
        double bfrag = Kbuf[buf][li][4 * tt + lg];  // B[k=lg][n=li]
        acc = __builtin_amdgcn_mfma_f64_16x16x4f64(qreg[tt], bfrag, acc, 0, 0, 0);
      }
      __builtin_amdgcn_s_setprio(0);
      const int col = cbeg + kt * 16 + li;
      const double wj = w[col];
#pragma unroll
      for (int v = 0; v < 4; ++v) {
        double e = exp_d(acc[v]);
        Zt[v] += e;
        Wt[v] = fma(e, wj, Wt[v]);
        if (e > Et[v]) { Et[v] = e; Jt[v] = col; }
      }
      __syncthreads();
    }

#pragma unroll
    for (int v = 0; v < 4; ++v) {
#pragma unroll
      for (int m = 1; m < 16; m <<= 1) {
        Zt[v] += __shfl_xor(Zt[v], m);
        Wt[v] += __shfl_xor(Wt[v], m);
        double e2 = __shfl_xor(Et[v], m);
        int j2 = __shfl_xor(Jt[v], m);
        if (e2 > Et[v] || (e2 == Et[v] && j2 < Jt[v])) { Et[v] = e2; Jt[v] = j2; }
      }
    }
    if (li == 0) {
#pragma unroll
      for (int v = 0; v < 4; ++v) {
        int row = rb + 16 * wv + lg + 4 * v;  // probe-validated: row = lg + 4*reg
        Zp[sp * NN + row] = Zt[v];
        Wp[sp * NN + row] = Wt[v];
        Ep[sp * NN + row] = Et[v];
        Jp[sp * NN + row] = Jt[v];
      }
    }
  }
  __syncthreads();  // Kbuf retired; P region safe to use

  // =================== phase B: k4 (r14 barrier-free body, SPATT=16) ===================
  {
    short (*P)[16 * 40] = (short (*)[16 * 40])smem;
    const int g = l >> 4, li = l & 15;
    const int qb = (blockIdx.x & 127) * 64 + wv * 16;
    const int sp = blockIdx.x >> 7;  // 0..SPATT-1
    short* Pw = &P[wv][0];
    const v8s q0 = *(const v8s*)(Qb + (size_t)(qb + li) * DH + g * 8);
    const v8s q1 = *(const v8s*)(Qb + (size_t)(qb + li) * DH + 32 + g * 8);
    v4f hacc[4];
#pragma unroll
    for (int db = 0; db < 4; ++db) hacc[db] = (v4f){0.f, 0.f, 0.f, 0.f};
    float zl = 0.f;
    const int kbeg = sp * (NN / SPATT);
    for (int jb = kbeg; jb < kbeg + NN / SPATT; jb += 32) {
      const bf16* kp = Kb + (size_t)(jb + li) * DH + g * 8;
      v8s ka0 = *(const v8s*)(kp);
      v8s ka1 = *(const v8s*)(kp + 32);
      v8s kb0 = *(const v8s*)(kp + 16 * DH);
      v8s kb1 = *(const v8s*)(kp + 16 * DH + 32);
      v4f c0 = (v4f){0.f, 0.f, 0.f, 0.f}, c1 = (v4f){0.f, 0.f, 0.f, 0.f};
      __builtin_amdgcn_s_setprio(1);
      c0 = MFMA16(ka0, q0, c0);
      c0 = MFMA16(ka1, q1, c0);
      c1 = MFMA16(kb0, q0, c1);
      c1 = MFMA16(kb1, q1, c1);
      __builtin_amdgcn_s_setprio(0);
      v4s p0, p1;
#pragma unroll
      for (int r = 0; r < 4; ++r) {
        short b0 = f2bfs(__expf(c0[r]));
        short b1 = f2bfs(__expf(c1[r]));
        p0[r] = b0;
        p1[r] = b1;
        zl += bf2f(*reinterpret_cast<bf16*>(&b0));
        zl += bf2f(*reinterpret_cast<bf16*>(&b1));
      }
      *(v4s*)&Pw[li * 40 + g * 4] = p0;
      *(v4s*)&Pw[li * 40 + 16 + g * 4] = p1;
      v8s pf = *(const v8s*)&Pw[li * 40 + g * 8];
#pragma unroll
      for (int db = 0; db < 4; ++db) {
        const v8s vb = *(const v8s*)(Vt + (size_t)(db * 16 + li) * NN + jb + g * 8);
        hacc[db] = MFMA16(pf, vb, hacc[db]);
      }
    }
    zl += __shfl_xor(zl, 16);
    zl += __shfl_xor(zl, 32);
    if (g == 0) zp[sp * NN + qb + li] = zl;
#pragma unroll
    for (int r = 0; r < 4; ++r) {
      int row = qb + g * 4 + r;
#pragma unroll
      for (int db = 0; db < 4; ++db)
        hp[((size_t)sp * NN + row) * DH + db * 16 + li] = hacc[db][r];
    }
  }
}

// ---------------- helpers (recompute tau/ex/j from split partials) ----------------
__device__ __forceinline__ double tau_of(int k, const double* __restrict__ Zp,
                                         const double* __restrict__ Wp) {
  double Z = 0, W = 0;
  for (int sp = 0; sp < SPLITS; ++sp) { Z += Zp[sp * NN + k]; W += Wp[sp * NN + k]; }
  return W / Z;
}
__device__ __forceinline__ void exj_of(int k, const double* __restrict__ Zp,
                                       const double* __restrict__ Ep, const int* __restrict__ Jp,
                                       int& exo, int& jo) {
  double Z = 0, E = -1;
  int J = 0;
  for (int sp = 0; sp < SPLITS; ++sp) {
    Z += Zp[sp * NN + k];
    double e = Ep[sp * NN + k];
    if (e > E || (e == E && Jp[sp * NN + k] < J)) { E = e; J = Jp[sp * NN + k]; }
  }
  exo = (E > 0.5 * Z) && (J != k);
  jo = J & (NN - 1);
}
__device__ __forceinline__ double tarr_of(int k, const double* __restrict__ Zp,
                                          const double* __restrict__ Wp,
                                          const double* __restrict__ Ep,
                                          const int* __restrict__ Jp, double cb) {
  int exk, jk;
  exj_of(k, Zp, Ep, Jp, exk, jk);
  double dk = exk ? RS2 : 1.0;
  double acc = dk * tau_of(k, Zp, Wp);
  if (exk) {
    int exj, jj;
    exj_of(jk, Zp, Ep, Jp, exj, jj);
    double dj = exj ? RS2 : 1.0;
    acc = fma(dj, tau_of(jk, Zp, Wp), acc);
  }
  return fma(dk, acc, cb);
}

__device__ __forceinline__ void k356_body(int i, const double* Zp, const double* Wp,
                                          const double* Ep, const int* Jp, const float* gb,
                                          const float* sW, const float* score_b,
                                          int* ex_out, int* jm_out, double* pre,
                                          float* sc32, int* cnt) {
  double cb = 0.0;
  for (int d = 0; d < DH; ++d) cb = fma((double)gb[d], (double)sW[d], cb);
  int exi, ji;
  exj_of(i, Zp, Ep, Jp, exi, ji);
  ex_out[i] = exi;
  jm_out[i] = ji;
  double di = exi ? RS2 : 1.0;
  double acc = di * tarr_of(i, Zp, Wp, Ep, Jp, cb);
  if (exi) {
    int exj, jj;
    exj_of(ji, Zp, Ep, Jp, exj, jj);
    double dj = exj ? RS2 : 1.0;
    acc = fma(dj, tarr_of(ji, Zp, Wp, Ep, Jp, cb), acc);
  }
  double p = fma(di, acc, (double)score_b[0]);
  pre[i] = p;
  sc32[i] = (float)tanh(p);
  cnt[i] = 0;
}

// ---------------- K_TAIL: cooperative fused tail (k9 + k356 | k7 | k8 | k11) --------------
__global__ __launch_bounds__(256) void k_tail(
    const float* __restrict__ hp, const float* __restrict__ zp, const float* __restrict__ gW,
    float* __restrict__ M,
    const double* __restrict__ Zp, const double* __restrict__ Wp,
    const double* __restrict__ Ep, const int* __restrict__ Jp,
    const float* __restrict__ gb, const float* __restrict__ sW, const float* __restrict__ sb,
    int* __restrict__ ex, int* __restrict__ jm, double* __restrict__ pre,
    float* __restrict__ sc32, int* __restrict__ cnt, int* __restrict__ sel,
    const float* __restrict__ lg, const float* __restrict__ lb,
    const float* __restrict__ hW, const float* __restrict__ hb, float* __restrict__ out) {
  cg::grid_group grid = cg::this_grid();
  __shared__ __align__(16) char smem[2048];
  const int t = threadIdx.x, bid = blockIdx.x;

  // ---- P1a: k9_hM (2 sweeps of 4096 rows over 1024 blocks) ----
  {
    float (*xs)[DH] = (float (*)[DH])smem;
    int sub = t >> 6, d = t & 63;
    for (int sw = 0; sw < 2; ++sw) {
      int n = sw * 4096 + bid * 4 + sub;
      float Z = 0.f, H = 0.f;
#pragma unroll
      for (int sp = 0; sp < SPATT; ++sp) {
        Z += zp[sp * NN + n];
        H += hp[((size_t)sp * NN + n) * DH + d];
      }
      xs[sub][d] = H / Z;
      __syncthreads();
      float acc = 0.f;
#pragma unroll 8
      for (int c = 0; c < DH; ++c) acc = fmaf(xs[sub][c], gW[c * DH + d], acc);
      M[(size_t)n * DH + d] = acc;
      __syncthreads();
    }
  }
  // ---- P1b: k356 (blocks 0..31) ----
  if (bid < 32) k356_body(bid * 256 + t, Zp, Wp, Ep, Jp, gb, sW, sb, ex, jm, pre, sc32, cnt);
  grid.sync();

  // ---- P2: k7_rank (1024 blocks = 32 i-chunks x 32 j-chunks of 256) ----
  {
    double* pj = (double*)smem;
    int i = (bid & 31) * 256 + t;
    int j0 = (bid >> 5) * 256;
    pj[t] = pre[j0 + t];
    __syncthreads();
    double si = pre[i];
    int c = 0;
#pragma unroll 8
    for (int j = 0; j < 256; ++j) {
      double v = pj[j];
      c += (v > si || (v == si && (j0 + j) < i));
    }
    atomicAdd(&cnt[i], c);
  }
  grid.sync();

  // ---- P3: k8_sel (blocks 0..31) ----
  if (bid < 32) {
    int i = bid * 256 + t;
    unsigned r = (unsigned)cnt[i];
    if (r < KKEEP) sel[r] = i;
  }
  grid.sync();

  // ---- P4: k11_head (all 1024 blocks) ----
  {
    float (*xs)[DH] = (float (*)[DH])smem;
    int wv = t >> 6, d = t & 63;
    int p = bid * 4 + wv;
    int i = sel[p] & (NN - 1);
    int exi = ex[i];
    float di = exi ? 0.70710678f : 1.0f;
    float acc0 = di * M[(size_t)i * DH + d];
    if (exi) {
      int j = jm[i] & (NN - 1);
      acc0 = fmaf(ex[j] ? 0.70710678f : 1.0f, M[(size_t)j * DH + d], acc0);
    }
    float gval = fmaf(di, acc0, gb[d]);
    float v = gval * sc32[i];
    float s1 = v;
#pragma unroll
    for (int off = 32; off; off >>= 1) s1 += __shfl_xor(s1, off);
    float mu = s1 * (1.0f / 64.0f);
    float dv = v - mu;
    float s2 = dv * dv;
#pragma unroll
    for (int off = 32; off; off >>= 1) s2 += __shfl_xor(s2, off);
    float var = s2 * (1.0f / 64.0f);
    float xn = dv * rsqrtf(var + 1e-5f) * lg[d] + lb[d];
    xs[wv][d] = fmaxf(xn, 0.0f);
    __syncthreads();
    if (t < 128) {
      int r = t >> 5, o = t & 31;
      float acc = hb[o];
#pragma unroll 8
      for (int c = 0; c < DH; ++c) acc = fmaf(xs[r][c], hW[c * DOUT + o], acc);
      out[(size_t)(bid * 4 + r) * DOUT + o] = acc;
    }
  }
}

// ---------------- fallback (r18-proven) tail kernels ----------------
__global__ void k356(const double* __restrict__ Zp, const double* __restrict__ Wp,
                     const double* __restrict__ Ep, const int* __restrict__ Jp,
                     const float* __restrict__ gb, const float* __restrict__ sW,
                     const float* __restrict__ score_b,
                     int* __restrict__ ex_out, int* __restrict__ jm_out,
                     double* __restrict__ pre, float* __restrict__ sc32, int* __restrict__ cnt) {
  int i = blockIdx.x * 256 + threadIdx.x;
  k356_body(i, Zp, Wp, Ep, Jp, gb, sW, score_b, ex_out, jm_out, pre, sc32, cnt);
}

__global__ __launch_bounds__(256) void k9_hM(const float* __restrict__ hp, const float* __restrict__ zp,
                                             const float* __restrict__ gW, float* __restrict__ M) {
  __shared__ float xs[4][DH];
  int t = threadIdx.x;
  int sub = t >> 6, d = t & 63;
  int n = blockIdx.x * 4 + sub;
  float Z = 0.f, H = 0.f;
#pragma unroll
  for (int sp = 0; sp < SPATT; ++sp) {
    Z += zp[sp * NN + n];
    H += hp[((size_t)sp * NN + n) * DH + d];
  }
  xs[sub][d] = H / Z;
  __syncthreads();
  float acc = 0.f;
#pragma unroll 8
  for (int c = 0; c < DH; ++c) acc = fmaf(xs[sub][c], gW[c * DH + d], acc);
  M[(size_t)n * DH + d] = acc;
}

__global__ void k7_rank(const double* __restrict__ pre, int* __restrict__ cnt) {
  __shared__ double pj[512];
  int i = (blockIdx.x & 31) * 256 + threadIdx.x;
  int j0 = (blockIdx.x >> 5) * 512;
  for (int k = threadIdx.x; k < 512; k += 256) pj[k] = pre[j0 + k];
  __syncthreads();
  double si = pre[i];
  int c = 0;
#pragma unroll 8
  for (int j = 0; j < 512; ++j) {
    double v = pj[j];
    c += (v > si || (v == si && (j0 + j) < i));
  }
  atomicAdd(&cnt[i], c);
}

__global__ void k8_sel(const int* __restrict__ cnt, int* __restrict__ sel) {
  int i = blockIdx.x * 256 + threadIdx.x;
  unsigned r = (unsigned)cnt[i];
  if (r < KKEEP) sel[r] = i;
}

__global__ __launch_bounds__(256) void k11_head(const float* __restrict__ M, const int* __restrict__ extra,
                                                const int* __restrict__ jmA, const float* __restrict__ gb,
                                                const float* __restrict__ sc32, const int* __restrict__ sel,
                                                const float* __restrict__ lg, const float* __restrict__ lb,
                                                const float* __restrict__ hW, const float* __restrict__ hb,
                                                float* __restrict__ out) {
  __shared__ float xs[4][DH];
  int t = threadIdx.x;
  int wv = t >> 6, d = t & 63;
  int p = blockIdx.x * 4 + wv;
  int i = sel[p] & (NN - 1);
  int ex = extra[i];
  float di = ex ? 0.70710678f : 1.0f;
  float acc0 = di * M[(size_t)i * DH + d];
  if (ex) {
    int j = jmA[i] & (NN - 1);
    acc0 = fmaf(extra[j] ? 0.70710678f : 1.0f, M[(size_t)j * DH + d], acc0);
  }
  float gval = fmaf(di, acc0, gb[d]);
  float v = gval * sc32[i];
  float s1 = v;
#pragma unroll
  for (int off = 32; off; off >>= 1) s1 += __shfl_xor(s1, off);
  float mu = s1 * (1.0f / 64.0f);
  float dv = v - mu;
  float s2 = dv * dv;
#pragma unroll
  for (int off = 32; off; off >>= 1) s2 += __shfl_xor(s2, off);
  float var = s2 * (1.0f / 64.0f);
  float xn = dv * rsqrtf(var + 1e-5f) * lg[d] + lb[d];
  xs[wv][d] = fmaxf(xn, 0.0f);
  __syncthreads();
  if (t < 128) {
    int r = t >> 5, o = t & 31;
    float acc = hb[o];
#pragma unroll 8
    for (int c = 0; c < DH; ++c) acc = fmaf(xs[r][c], hW[c * DOUT + o], acc);
    out[(size_t)(blockIdx.x * 4 + r) * DOUT + o] = acc;
  }
}

// ---------------- workspace layout (MB-granular, no aliasing; ws = 256 MB) ----------------
#define MB 1048576ull
constexpr size_t OFF_QD   = 0 * MB;    // f64 4MB
constexpr size_t OFF_KD   = 4 * MB;    // f64 4MB
constexpr size_t OFF_M    = 16 * MB;   // f32 2MB
constexpr size_t OFF_ZP   = 20 * MB;   // f64 16*8192 = 1MB
constexpr size_t OFF_WP   = 21 * MB;   // f64 1MB
constexpr size_t OFF_EP   = 22 * MB;   // f64 1MB
constexpr size_t OFF_JP   = 23 * MB;   // i32 512KB
constexpr size_t OFF_W    = 24 * MB;   // f64 8192
constexpr size_t OFF_EX   = 27 * MB;
constexpr size_t OFF_JM   = 28 * MB;
constexpr size_t OFF_PRE  = 30 * MB;
constexpr size_t OFF_SC   = 31 * MB;
constexpr size_t OFF_CNT  = 32 * MB;
constexpr size_t OFF_SEL  = 33 * MB;
constexpr size_t OFF_HP   = 34 * MB;   // f32 SPATT*8192*64 = 32MB
constexpr size_t OFF_ZATT = 66 * MB;   // f32 SPATT*8192 = 512KB
constexpr size_t OFF_QB   = 67 * MB;   // bf16 1MB
constexpr size_t OFF_KB   = 68 * MB;   // bf16 1MB
constexpr size_t OFF_VT   = 69 * MB;   // bf16 1MB (V^T [DH][NN])
constexpr size_t WS_NEEDED = 70 * MB;

extern "C" void kernel_launch(void* const* d_in, const int* in_sizes, int n_in,
                              void* d_out, int out_size, void* d_ws, size_t ws_size,
                              hipStream_t stream) {
  if (n_in < 16 || ws_size < WS_NEEDED || out_size != KKEEP * DOUT) {
    fprintf(stderr, "[sag] GUARD ws=%zu need=%zu n_in=%d out=%d\n", ws_size, WS_NEEDED, n_in, out_size);
    return;
  }
  const float* x   = (const float*)d_in[0];
  const float* Wq  = (const float*)d_in[2];
  const float* bq  = (const float*)d_in[3];
  const float* Wk  = (const float*)d_in[4];
  const float* bk  = (const float*)d_in[5];
  const float* Wv  = (const float*)d_in[6];
  const float* bv  = (const float*)d_in[7];
  const float* gW  = (const float*)d_in[8];
  const float* gb  = (const float*)d_in[9];
  const float* sW  = (const float*)d_in[10];
  const float* sb  = (const float*)d_in[11];
  const float* lg  = (const float*)d_in[12];
  const float* lb  = (const float*)d_in[13];
  const float* hW  = (const float*)d_in[14];
  const float* hb  = (const float*)d_in[15];
  float* out = (float*)d_out;

  char* ws = (char*)d_ws;
  double* Qd  = (double*)(ws + OFF_QD);
  double* Kd  = (double*)(ws + OFF_KD);
  bf16*   Qb  = (bf16*)(ws + OFF_QB);
  bf16*   Kb  = (bf16*)(ws + OFF_KB);
  bf16*   Vt  = (bf16*)(ws + OFF_VT);
  float*  M   = (float*)(ws + OFF_M);
  double* Zp  = (double*)(ws + OFF_ZP);
  double* Wp  = (double*)(ws + OFF_WP);
  double* Ep  = (double*)(ws + OFF_EP);
  int*    Jp  = (int*)(ws + OFF_JP);
  double* w   = (double*)(ws + OFF_W);
  int*    ex  = (int*)(ws + OFF_EX);
  int*    jm  = (int*)(ws + OFF_JM);
  double* pre = (double*)(ws + OFF_PRE);
  float*  sc32= (float*)(ws + OFF_SC);
  int*    cnt = (int*)(ws + OFF_CNT);
  int*    sel = (int*)(ws + OFF_SEL);
  float*  hp  = (float*)(ws + OFF_HP);
  float*  zatt= (float*)(ws + OFF_ZATT);

  hipLaunchKernelGGL(k1_prep, dim3(512), dim3(256), 0, stream, x, Wq, bq, Wk, bk, Wv, bv,
                     gW, sW, Qd, Kd, w, Qb, Kb, Vt);
  hipLaunchKernelGGL(k24_seq, dim3(128 * SPLITS), dim3(256), 0, stream,
                     Qd, Kd, w, Zp, Wp, Ep, Jp, Qb, Kb, Vt, hp, zatt);

  void* kargs[] = {&hp, &zatt, &gW, &M, &Zp, &Wp, &Ep, &Jp, &gb, &sW, &sb,
                   &ex, &jm, &pre, &sc32, &cnt, &sel, &lg, &lb, &hW, &hb, &out};
  hipError_t ce = hipLaunchCooperativeKernel((const void*)k_tail, dim3(1024), dim3(256),
                                             kargs, 0, stream);
  if (ce != hipSuccess) {
    // fallback: proven r18 tail
    hipLaunchKernelGGL(k9_hM, dim3(2048), dim3(256), 0, stream, hp, zatt, gW, M);
    hipLaunchKernelGGL(k356, dim3(32), dim3(256), 0, stream, Zp, Wp, Ep, Jp, gb, sW, sb,
                       ex, jm, pre, sc32, cnt);
    hipLaunchKernelGGL(k7_rank, dim3(512), dim3(256), 0, stream, pre, cnt);
    hipLaunchKernelGGL(k8_sel, dim3(32), dim3(256), 0, stream, cnt, sel);
    hipLaunchKernelGGL(k11_head, dim3(1024), dim3(256), 0, stream, M, ex, jm, gb, sc32, sel,
                       lg, lb, hW, hb, out);
  }
}

// Round 20
// 348.260 us; speedup vs baseline: 1.8610x; 1.8610x over previous
//
#include <hip/hip_runtime.h>
#include <hip/hip_bf16.h>
#include <cstdio>

typedef __hip_bfloat16 bf16;
typedef __attribute__((ext_vector_type(8))) short v8s;
typedef __attribute__((ext_vector_type(4))) short v4s;
typedef __attribute__((ext_vector_type(4))) float v4f;
typedef __attribute__((ext_vector_type(4))) double v4d;

#define MFMA16(a, b, c) __builtin_amdgcn_mfma_f32_16x16x32_bf16((a), (b), (c), 0, 0, 0)

#define NN 8192
#define DIN 128
#define DH 64
#define DOUT 32
#define KKEEP 4096
#define SPLITS 16  // k2 kv-splits
#define SPATT 16   // k4 kv-splits (matched to SPLITS for uniform fused blocks)
#define RS2 0.70710678118654752440

__device__ __forceinline__ float bf2f(bf16 v) { return __bfloat162float(v); }
__device__ __forceinline__ short f2bfs(float f) {
  __hip_bfloat16 h = __float2bfloat16(f);
  return *reinterpret_cast<short*>(&h);
}
__device__ __forceinline__ bf16 f2bf(float v) { return __float2bfloat16(v); }

// f64 exp, rel err ~7e-12 over |s|<=25
__device__ __forceinline__ double exp_d(double s) {
  const double L2E    = 1.4426950408889634074;
  const double LN2_HI = 6.93147180369123816490e-01;
  const double LN2_LO = 1.90821492927058770002e-10;
  double t  = s * L2E;
  double kf = rint(t);
  double r  = fma(-kf, LN2_HI, s);
  r = fma(-kf, LN2_LO, r);
  double p = 1.0 / 362880.0;
  p = fma(p, r, 1.0 / 40320.0);
  p = fma(p, r, 1.0 / 5040.0);
  p = fma(p, r, 1.0 / 720.0);
  p = fma(p, r, 1.0 / 120.0);
  p = fma(p, r, 1.0 / 24.0);
  p = fma(p, r, 1.0 / 6.0);
  p = fma(p, r, 0.5);
  p = fma(p, r, 1.0);
  p = fma(p, r, 1.0);
  int k = (int)kf;
  long long bits = ((long long)(1023 + k)) << 52;
  double sc = __longlong_as_double(bits);
  return p * sc;
}

// ---------------- K1: u inline; Q(pre-scaled),K f64; Qb,Kb,V^T bf16; w = V.u ----------------
__global__ __launch_bounds__(256) void k1_prep(
    const float* __restrict__ x, const float* __restrict__ Wq, const float* __restrict__ bq,
    const float* __restrict__ Wk, const float* __restrict__ bk, const float* __restrict__ Wv,
    const float* __restrict__ bv, const float* __restrict__ gW, const float* __restrict__ sW,
    double* __restrict__ Qd, double* __restrict__ Kd, double* __restrict__ w,
    bf16* __restrict__ Qb, bf16* __restrict__ Kb, bf16* __restrict__ Vt) {
  __shared__ double xs[16][DIN];
  int t = threadIdx.x;
  int nb = blockIdx.x * 16;
  for (int idx = t; idx < 16 * DIN; idx += 256)
    xs[idx >> 7][idx & 127] = (double)x[(size_t)nb * DIN + idx];
  __syncthreads();
  int d = t & 63;
  int sub = t >> 6;
  double ud = 0.0;
  for (int dd = 0; dd < DH; ++dd) ud = fma((double)gW[d * DH + dd], (double)sW[dd], ud);
  double bqd = (double)bq[d];
  double bkd = (double)bk[d];
  double bvd = (double)bv[d];
  for (int pass = 0; pass < 4; ++pass) {
    int n = pass * 4 + sub;
    double aq = bqd, ak = bkd, av = bvd;
#pragma unroll 8
    for (int c = 0; c < DIN; ++c) {
      double xv = xs[n][c];
      aq = fma(xv, (double)Wq[c * DH + d], aq);
      ak = fma(xv, (double)Wk[c * DH + d], ak);
      av = fma(xv, (double)Wv[c * DH + d], av);
    }
    aq *= 0.125;  // fold 1/sqrt(64), exact
    int node = nb + n;
    Qd[(size_t)node * DH + d] = aq;
    Kd[(size_t)node * DH + d] = ak;
    Qb[(size_t)node * DH + d] = f2bf((float)aq);
    Kb[(size_t)node * DH + d] = f2bf((float)ak);
    Vt[(size_t)d * NN + node] = f2bf((float)av);
    double pw = av * ud;
#pragma unroll
    for (int off = 32; off; off >>= 1) pw += __shfl_xor(pw, off);
    if (d == 0) w[node] = pw;
  }
}

// ---------------- K24: uniform sequential fusion — phase A = k2 chunk, phase B = k4 chunk --
// grid 2048; every block does one k2 chunk (SPLITS=16 x 128 rb) then one k4 chunk (SPATT=16).
__global__ __launch_bounds__(256) void k24_seq(
    const double* __restrict__ Qd, const double* __restrict__ Kd, const double* __restrict__ w,
    double* __restrict__ Zp, double* __restrict__ Wp, double* __restrict__ Ep, int* __restrict__ Jp,
    const bf16* __restrict__ Qb, const bf16* __restrict__ Kb, const bf16* __restrict__ Vt,
    float* __restrict__ hp, float* __restrict__ zp) {
  __shared__ __align__(16) char smem[16896];  // union: Kbuf[2][16][66] f64 | P[4][640] short
  const int t = threadIdx.x;
  const int wv = t >> 6;
  const int l = t & 63;

  // =================== phase A: k2 (r15 proven body) ===================
  {
    double (*Kbuf)[16][66] = (double (*)[16][66])smem;
    const int li = l & 15, lg = l >> 4;
    const int rb = (blockIdx.x & 127) * 64;
    const int sp = blockIdx.x >> 7;  // 0..SPLITS-1
    const int cbeg = sp * (NN / SPLITS);

    double qreg[16];
    const double* qrow = Qd + (size_t)(rb + 16 * wv + li) * DH + lg;
#pragma unroll
    for (int tt = 0; tt < 16; ++tt) qreg[tt] = qrow[4 * tt];

    {
      const double* src = Kd + (size_t)cbeg * DH;
      int r = t >> 4, c = (t & 15) * 4;
      *(double2*)&Kbuf[0][r][c]     = *(const double2*)&src[r * DH + c];
      *(double2*)&Kbuf[0][r][c + 2] = *(const double2*)&src[r * DH + c + 2];
    }
    __syncthreads();

    double Zt[4] = {0, 0, 0, 0}, Wt[4] = {0, 0, 0, 0}, Et[4] = {-1, -1, -1, -1};
    int Jt[4] = {0, 0, 0, 0};

    const int NT = (NN / SPLITS) / 16;  // 32 tiles
    for (int kt = 0; kt < NT; ++kt) {
      const int buf = kt & 1;
      if (kt + 1 < NT) {
        const double* src = Kd + (size_t)(cbeg + (kt + 1) * 16) * DH;
        int r = t >> 4, c = (t & 15) * 4;
        *(double2*)&Kbuf[buf ^ 1][r][c]     = *(const double2*)&src[r * DH + c];
        *(double2*)&Kbuf[buf ^ 1][r][c + 2] = *(const double2*)&src[r * DH + c + 2];
      }
      v4d acc = (v4d){0.0, 0.0, 0.0, 0.0};
      __builtin_amdgcn_s_setprio(1);
#pragma unroll
      for (int tt = 0; tt < 16; ++tt) {
        double bfrag = Kbuf[buf][li][4 * tt + lg];  // B[k=lg][n=li]
        acc = __builtin_amdgcn_mfma_f64_16x16x4f64(qreg[tt], bfrag, acc, 0, 0, 0);
      }
      __builtin_amdgcn_s_setprio(0);
      const int col = cbeg + kt * 16 + li;
      const double wj = w[col];
#pragma unroll
      for (int v = 0; v < 4; ++v) {
        double e = exp_d(acc[v]);
        Zt[v] += e;
        Wt[v] = fma(e, wj, Wt[v]);
        if (e > Et[v]) { Et[v] = e; Jt[v] = col; }
      }
      __syncthreads();
    }

#pragma unroll
    for (int v = 0; v < 4; ++v) {
#pragma unroll
      for (int m = 1; m < 16; m <<= 1) {
        Zt[v] += __shfl_xor(Zt[v], m);
        Wt[v] += __shfl_xor(Wt[v], m);
        double e2 = __shfl_xor(Et[v], m);
        int j2 = __shfl_xor(Jt[v], m);
        if (e2 > Et[v] || (e2 == Et[v] && j2 < Jt[v])) { Et[v] = e2; Jt[v] = j2; }
      }
    }
    if (li == 0) {
#pragma unroll
      for (int v = 0; v < 4; ++v) {
        int row = rb + 16 * wv + lg + 4 * v;  // probe-validated: row = lg + 4*reg
        Zp[sp * NN + row] = Zt[v];
        Wp[sp * NN + row] = Wt[v];
        Ep[sp * NN + row] = Et[v];
        Jp[sp * NN + row] = Jt[v];
      }
    }
  }
  __syncthreads();  // Kbuf retired; P region safe to use

  // =================== phase B: k4 (r14 barrier-free body, SPATT=16) ===================
  {
    short (*P)[16 * 40] = (short (*)[16 * 40])smem;
    const int g = l >> 4, li = l & 15;
    const int qb = (blockIdx.x & 127) * 64 + wv * 16;
    const int sp = blockIdx.x >> 7;  // 0..SPATT-1
    short* Pw = &P[wv][0];
    const v8s q0 = *(const v8s*)(Qb + (size_t)(qb + li) * DH + g * 8);
    const v8s q1 = *(const v8s*)(Qb + (size_t)(qb + li) * DH + 32 + g * 8);
    v4f hacc[4];
#pragma unroll
    for (int db = 0; db < 4; ++db) hacc[db] = (v4f){0.f, 0.f, 0.f, 0.f};
    float zl = 0.f;
    const int kbeg = sp * (NN / SPATT);
    for (int jb = kbeg; jb < kbeg + NN / SPATT; jb += 32) {
      const bf16* kp = Kb + (size_t)(jb + li) * DH + g * 8;
      v8s ka0 = *(const v8s*)(kp);
      v8s ka1 = *(const v8s*)(kp + 32);
      v8s kb0 = *(const v8s*)(kp + 16 * DH);
      v8s kb1 = *(const v8s*)(kp + 16 * DH + 32);
      v4f c0 = (v4f){0.f, 0.f, 0.f, 0.f}, c1 = (v4f){0.f, 0.f, 0.f, 0.f};
      __builtin_amdgcn_s_setprio(1);
      c0 = MFMA16(ka0, q0, c0);
      c0 = MFMA16(ka1, q1, c0);
      c1 = MFMA16(kb0, q0, c1);
      c1 = MFMA16(kb1, q1, c1);
      __builtin_amdgcn_s_setprio(0);
      v4s p0, p1;
#pragma unroll
      for (int r = 0; r < 4; ++r) {
        short b0 = f2bfs(__expf(c0[r]));
        short b1 = f2bfs(__expf(c1[r]));
        p0[r] = b0;
        p1[r] = b1;
        zl += bf2f(*reinterpret_cast<bf16*>(&b0));
        zl += bf2f(*reinterpret_cast<bf16*>(&b1));
      }
      // wave-private P: intra-wave ds_write -> ds_read ordered by in-order DS pipe + lgkmcnt.
      *(v4s*)&Pw[li * 40 + g * 4] = p0;
      *(v4s*)&Pw[li * 40 + 16 + g * 4] = p1;
      v8s pf = *(const v8s*)&Pw[li * 40 + g * 8];
#pragma unroll
      for (int db = 0; db < 4; ++db) {
        const v8s vb = *(const v8s*)(Vt + (size_t)(db * 16 + li) * NN + jb + g * 8);
        hacc[db] = MFMA16(pf, vb, hacc[db]);
      }
    }
    zl += __shfl_xor(zl, 16);
    zl += __shfl_xor(zl, 32);
    if (g == 0) zp[sp * NN + qb + li] = zl;
#pragma unroll
    for (int r = 0; r < 4; ++r) {
      int row = qb + g * 4 + r;
#pragma unroll
      for (int db = 0; db < 4; ++db)
        hp[((size_t)sp * NN + row) * DH + db * 16 + li] = hacc[db][r];
    }
  }
}

// ---------------- helpers for K356 (recompute tau/ex/j from split partials) ----------------
__device__ __forceinline__ double tau_of(int k, const double* __restrict__ Zp,
                                         const double* __restrict__ Wp) {
  double Z = 0, W = 0;
  for (int sp = 0; sp < SPLITS; ++sp) { Z += Zp[sp * NN + k]; W += Wp[sp * NN + k]; }
  return W / Z;
}
__device__ __forceinline__ void exj_of(int k, const double* __restrict__ Zp,
                                       const double* __restrict__ Ep, const int* __restrict__ Jp,
                                       int& exo, int& jo) {
  double Z = 0, E = -1;
  int J = 0;
  for (int sp = 0; sp < SPLITS; ++sp) {
    Z += Zp[sp * NN + k];
    double e = Ep[sp * NN + k];
    if (e > E || (e == E && Jp[sp * NN + k] < J)) { E = e; J = Jp[sp * NN + k]; }
  }
  exo = (E > 0.5 * Z) && (J != k);
  jo = J & (NN - 1);
}
__device__ __forceinline__ double tarr_of(int k, const double* __restrict__ Zp,
                                          const double* __restrict__ Wp,
                                          const double* __restrict__ Ep,
                                          const int* __restrict__ Jp, double cb) {
  int exk, jk;
  exj_of(k, Zp, Ep, Jp, exk, jk);
  double dk = exk ? RS2 : 1.0;
  double acc = dk * tau_of(k, Zp, Wp);
  if (exk) {
    int exj, jj;
    exj_of(jk, Zp, Ep, Jp, exj, jj);
    double dj = exj ? RS2 : 1.0;
    acc = fma(dj, tau_of(jk, Zp, Wp), acc);
  }
  return fma(dk, acc, cb);
}

// ---------------- K356: fused combine + An@tau + An@tarr -> ex, jm, pre, sc32, cnt -------
__global__ void k356(const double* __restrict__ Zp, const double* __restrict__ Wp,
                     const double* __restrict__ Ep, const int* __restrict__ Jp,
                     const float* __restrict__ gb, const float* __restrict__ sW,
                     const float* __restrict__ score_b,
                     int* __restrict__ ex_out, int* __restrict__ jm_out,
                     double* __restrict__ pre, float* __restrict__ sc32, int* __restrict__ cnt) {
  int i = blockIdx.x * 256 + threadIdx.x;
  double cb = 0.0;
  for (int d = 0; d < DH; ++d) cb = fma((double)gb[d], (double)sW[d], cb);
  int exi, ji;
  exj_of(i, Zp, Ep, Jp, exi, ji);
  ex_out[i] = exi;
  jm_out[i] = ji;
  double di = exi ? RS2 : 1.0;
  double acc = di * tarr_of(i, Zp, Wp, Ep, Jp, cb);
  if (exi) {
    int exj, jj;
    exj_of(ji, Zp, Ep, Jp, exj, jj);
    double dj = exj ? RS2 : 1.0;
    acc = fma(dj, tarr_of(ji, Zp, Wp, Ep, Jp, cb), acc);
  }
  double p = fma(di, acc, (double)score_b[0]);
  pre[i] = p;
  sc32[i] = (float)tanh(p);
  cnt[i] = 0;
}

// ---------------- K9: fused combine + M = h @ gcn_W (f32) ----------------
__global__ __launch_bounds__(256) void k9_hM(const float* __restrict__ hp, const float* __restrict__ zp,
                                             const float* __restrict__ gW, float* __restrict__ M) {
  __shared__ float xs[4][DH];
  int t = threadIdx.x;
  int sub = t >> 6, d = t & 63;
  int n = blockIdx.x * 4 + sub;
  float Z = 0.f, H = 0.f;
#pragma unroll
  for (int sp = 0; sp < SPATT; ++sp) {
    Z += zp[sp * NN + n];
    H += hp[((size_t)sp * NN + n) * DH + d];
  }
  xs[sub][d] = H / Z;
  __syncthreads();
  float acc = 0.f;
#pragma unroll 8
  for (int c = 0; c < DH; ++c) acc = fmaf(xs[sub][c], gW[c * DH + d], acc);
  M[(size_t)n * DH + d] = acc;
}

// ---------------- K7: exact rank count (value desc, index asc) — LDS-staged j-tile --------
__global__ void k7_rank(const double* __restrict__ pre, int* __restrict__ cnt) {
  __shared__ double pj[512];
  int i = (blockIdx.x & 31) * 256 + threadIdx.x;
  int j0 = (blockIdx.x >> 5) * 512;
  for (int k = threadIdx.x; k < 512; k += 256) pj[k] = pre[j0 + k];
  __syncthreads();
  double si = pre[i];
  int c = 0;
#pragma unroll 8
  for (int j = 0; j < 512; ++j) {
    double v = pj[j];
    c += (v > si || (v == si && (j0 + j) < i));
  }
  atomicAdd(&cnt[i], c);
}

// ---------------- K8: scatter selection ----------------
__global__ void k8_sel(const int* __restrict__ cnt, int* __restrict__ sel) {
  int i = blockIdx.x * 256 + threadIdx.x;
  unsigned r = (unsigned)cnt[i];
  if (r < KKEEP) sel[r] = i;
}

// ---------------- K11: fused An-apply + gather + LN + ReLU + head -> out f32 ----------------
__global__ __launch_bounds__(256) void k11_head(const float* __restrict__ M, const int* __restrict__ extra,
                                                const int* __restrict__ jmA, const float* __restrict__ gb,
                                                const float* __restrict__ sc32, const int* __restrict__ sel,
                                                const float* __restrict__ lg, const float* __restrict__ lb,
                                                const float* __restrict__ hW, const float* __restrict__ hb,
                                                float* __restrict__ out) {
  __shared__ float xs[4][DH];
  int t = threadIdx.x;
  int wv = t >> 6, d = t & 63;
  int p = blockIdx.x * 4 + wv;
  int i = sel[p] & (NN - 1);
  int ex = extra[i];
  float di = ex ? 0.70710678f : 1.0f;
  float acc0 = di * M[(size_t)i * DH + d];
  if (ex) {
    int j = jmA[i] & (NN - 1);
    acc0 = fmaf(extra[j] ? 0.70710678f : 1.0f, M[(size_t)j * DH + d], acc0);
  }
  float gval = fmaf(di, acc0, gb[d]);
  float v = gval * sc32[i];
  float s1 = v;
#pragma unroll
  for (int off = 32; off; off >>= 1) s1 += __shfl_xor(s1, off);
  float mu = s1 * (1.0f / 64.0f);
  float dv = v - mu;
  float s2 = dv * dv;
#pragma unroll
  for (int off = 32; off; off >>= 1) s2 += __shfl_xor(s2, off);
  float var = s2 * (1.0f / 64.0f);
  float xn = dv * rsqrtf(var + 1e-5f) * lg[d] + lb[d];
  xs[wv][d] = fmaxf(xn, 0.0f);
  __syncthreads();
  if (t < 128) {
    int r = t >> 5, o = t & 31;
    float acc = hb[o];
#pragma unroll 8
    for (int c = 0; c < DH; ++c) acc = fmaf(xs[r][c], hW[c * DOUT + o], acc);
    out[(size_t)(blockIdx.x * 4 + r) * DOUT + o] = acc;
  }
}

// ---------------- workspace layout (MB-granular, no aliasing; ws = 256 MB) ----------------
#define MB 1048576ull
constexpr size_t OFF_QD   = 0 * MB;    // f64 4MB
constexpr size_t OFF_KD   = 4 * MB;    // f64 4MB
constexpr size_t OFF_M    = 16 * MB;   // f32 2MB
constexpr size_t OFF_ZP   = 20 * MB;   // f64 16*8192 = 1MB
constexpr size_t OFF_WP   = 21 * MB;   // f64 1MB
constexpr size_t OFF_EP   = 22 * MB;   // f64 1MB
constexpr size_t OFF_JP   = 23 * MB;   // i32 512KB
constexpr size_t OFF_W    = 24 * MB;   // f64 8192
constexpr size_t OFF_EX   = 27 * MB;
constexpr size_t OFF_JM   = 28 * MB;
constexpr size_t OFF_PRE  = 30 * MB;
constexpr size_t OFF_SC   = 31 * MB;
constexpr size_t OFF_CNT  = 32 * MB;
constexpr size_t OFF_SEL  = 33 * MB;
constexpr size_t OFF_HP   = 34 * MB;   // f32 SPATT*8192*64 = 32MB
constexpr size_t OFF_ZATT = 66 * MB;   // f32 SPATT*8192 = 512KB
constexpr size_t OFF_QB   = 67 * MB;   // bf16 1MB
constexpr size_t OFF_KB   = 68 * MB;   // bf16 1MB
constexpr size_t OFF_VT   = 69 * MB;   // bf16 1MB (V^T [DH][NN])
constexpr size_t WS_NEEDED = 70 * MB;

extern "C" void kernel_launch(void* const* d_in, const int* in_sizes, int n_in,
                              void* d_out, int out_size, void* d_ws, size_t ws_size,
                              hipStream_t stream) {
  if (n_in < 16 || ws_size < WS_NEEDED || out_size != KKEEP * DOUT) {
    fprintf(stderr, "[sag] GUARD ws=%zu need=%zu n_in=%d out=%d\n", ws_size, WS_NEEDED, n_in, out_size);
    return;
  }
  const float* x   = (const float*)d_in[0];
  const float* Wq  = (const float*)d_in[2];
  const float* bq  = (const float*)d_in[3];
  const float* Wk  = (const float*)d_in[4];
  const float* bk  = (const float*)d_in[5];
  const float* Wv  = (const float*)d_in[6];
  const float* bv  = (const float*)d_in[7];
  const float* gW  = (const float*)d_in[8];
  const float* gb  = (const float*)d_in[9];
  const float* sW  = (const float*)d_in[10];
  const float* sb  = (const float*)d_in[11];
  const float* lg  = (const float*)d_in[12];
  const float* lb  = (const float*)d_in[13];
  const float* hW  = (const float*)d_in[14];
  const float* hb  = (const float*)d_in[15];
  float* out = (float*)d_out;

  char* ws = (char*)d_ws;
  double* Qd  = (double*)(ws + OFF_QD);
  double* Kd  = (double*)(ws + OFF_KD);
  bf16*   Qb  = (bf16*)(ws + OFF_QB);
  bf16*   Kb  = (bf16*)(ws + OFF_KB);
  bf16*   Vt  = (bf16*)(ws + OFF_VT);
  float*  M   = (float*)(ws + OFF_M);
  double* Zp  = (double*)(ws + OFF_ZP);
  double* Wp  = (double*)(ws + OFF_WP);
  double* Ep  = (double*)(ws + OFF_EP);
  int*    Jp  = (int*)(ws + OFF_JP);
  double* w   = (double*)(ws + OFF_W);
  int*    ex  = (int*)(ws + OFF_EX);
  int*    jm  = (int*)(ws + OFF_JM);
  double* pre = (double*)(ws + OFF_PRE);
  float*  sc32= (float*)(ws + OFF_SC);
  int*    cnt = (int*)(ws + OFF_CNT);
  int*    sel = (int*)(ws + OFF_SEL);
  float*  hp  = (float*)(ws + OFF_HP);
  float*  zatt= (float*)(ws + OFF_ZATT);

  hipLaunchKernelGGL(k1_prep, dim3(512), dim3(256), 0, stream, x, Wq, bq, Wk, bk, Wv, bv,
                     gW, sW, Qd, Kd, w, Qb, Kb, Vt);
  hipLaunchKernelGGL(k24_seq, dim3(128 * SPLITS), dim3(256), 0, stream,
                     Qd, Kd, w, Zp, Wp, Ep, Jp, Qb, Kb, Vt, hp, zatt);
  hipLaunchKernelGGL(k9_hM, dim3(2048), dim3(256), 0, stream, hp, zatt, gW, M);
  hipLaunchKernelGGL(k356, dim3(32), dim3(256), 0, stream, Zp, Wp, Ep, Jp, gb, sW, sb,
                     ex, jm, pre, sc32, cnt);
  hipLaunchKernelGGL(k7_rank, dim3(512), dim3(256), 0, stream, pre, cnt);
  hipLaunchKernelGGL(k8_sel, dim3(32), dim3(256), 0, stream, cnt, sel);
  hipLaunchKernelGGL(k11_head, dim3(1024), dim3(256), 0, stream, M, ex, jm, gb, sc32, sel,
                     lg, lb, hW, hb, out);
}